// Round 7
// baseline (1059.181 us; speedup 1.0000x reference)
//
#include <hip/hip_runtime.h>

typedef unsigned long long u64;
typedef unsigned int u32;
typedef unsigned short u16;
using bf16x8 = __attribute__((ext_vector_type(8))) __bf16;
using f32x16 = __attribute__((ext_vector_type(16))) float;

#define MQ 2048
#define ND 50000
#define DD 512

constexpr int NT    = 391;              // col-tiles of 128 (391*128 = 50048)
constexpr int NDPAD = NT * 128;         // padded R rows for bf16 arrays
constexpr int GY2   = 64;               // col-chunks -> grid 16x64 = 1024 blocks
constexpr int SHB   = 32768;            // LDS union: {stage 32KB | DS 64x128 | L}

__device__ __forceinline__ void insert10(u64 (&lst)[10], u64 key) {
  u64 cur = key;                        // lst sorted descending
#pragma unroll
  for (int p = 0; p < 10; ++p) {
    u64 a = lst[p];
    u64 mx = a > cur ? a : cur;
    cur    = a > cur ? cur : a;
    lst[p] = mx;
  }
}

__device__ __forceinline__ u32 bf_hi_rtn(float x) {   // bf16 RTNE, as bits
  u32 b = __float_as_uint(x);
  return (b + 0x7FFFu + ((b >> 16) & 1u)) >> 16;
}

__device__ __forceinline__ void gl_lds16(const void* g, void* l) {
  __builtin_amdgcn_global_load_lds(
      (const __attribute__((address_space(1))) u32*)g,
      (__attribute__((address_space(3))) u32*)l, 16, 0, 0);
}

// ---- kernel 1: fp32 -> bf16 hi/lo split + row sq-norms ----
__global__ __launch_bounds__(256) void convert_kernel(
    const float* __restrict__ Q, const float* __restrict__ R,
    u16* __restrict__ Qh, u16* __restrict__ Ql,
    u16* __restrict__ Rh, u16* __restrict__ Rl,
    float* __restrict__ rsq, float* __restrict__ qsq)
{
  const int wid  = blockIdx.x * 4 + (threadIdx.x >> 6);
  const int lane = threadIdx.x & 63;
  if (wid >= ND + MQ) return;
  const bool isR = wid < ND;
  const size_t row = isR ? (size_t)wid : (size_t)(wid - ND);
  const float* src = (isR ? R : Q) + row * DD;
  u16* hD = (isR ? Rh : Qh) + row * DD;
  u16* lD = (isR ? Rl : Ql) + row * DD;

  float s = 0.f;
#pragma unroll
  for (int it = 0; it < 2; ++it) {
    const int e = lane * 4 + it * 256;
    const float4 v = *reinterpret_cast<const float4*>(src + e);
    s += v.x * v.x + v.y * v.y + v.z * v.z + v.w * v.w;
    const u32 h0 = bf_hi_rtn(v.x), h1 = bf_hi_rtn(v.y), h2 = bf_hi_rtn(v.z), h3 = bf_hi_rtn(v.w);
    const u32 g0 = bf_hi_rtn(v.x - __uint_as_float(h0 << 16));
    const u32 g1 = bf_hi_rtn(v.y - __uint_as_float(h1 << 16));
    const u32 g2 = bf_hi_rtn(v.z - __uint_as_float(h2 << 16));
    const u32 g3 = bf_hi_rtn(v.w - __uint_as_float(h3 << 16));
    *reinterpret_cast<u64*>(hD + e) = (u64)h0 | ((u64)h1 << 16) | ((u64)h2 << 32) | ((u64)h3 << 48);
    *reinterpret_cast<u64*>(lD + e) = (u64)g0 | ((u64)g1 << 16) | ((u64)g2 << 32) | ((u64)g3 << 48);
  }
#pragma unroll
  for (int off = 32; off > 0; off >>= 1) s += __shfl_down(s, off, 64);
  if (lane == 0) {
    if (isR) rsq[row] = s;
    else     qsq[row] = s;
  }
}

// ---- kernel 2: MFMA GEMM-distance + fused top-10. BK=32, folded LDS layout,
// 33 KB LDS -> 4 blocks/CU. Logical row r, k-chunk c (8 elems) lives at LDS
// row r>>1, elem (r&1)*32 + ((c ^ ((r>>1)&3))<<3). Staging = linear LDS dest
// + pre-swizzled global source (rule 21). Dist/scan in two 64-row passes.
__global__ __launch_bounds__(256, 2) void knn_mfma_topk(
    const u16* __restrict__ Qhg, const u16* __restrict__ Qlg,
    const u16* __restrict__ Rhg, const u16* __restrict__ Rlg,
    const float* __restrict__ qsq, const float* __restrict__ rsq,
    u64* __restrict__ cand)
{
  __shared__ __align__(16) char shm[SHB];
  __shared__ float qs_lds[128];
  u16* Qh_l = (u16*)shm;                // [64 ldsrows][64 u16] = 8 KB each
  u16* Ql_l = Qh_l + 4096;
  u16* Rh_l = Ql_l + 4096;
  u16* Rl_l = Rh_l + 4096;
  u32* DS = (u32*)shm;                  // [64][128] dist keys (post-K)
  u64* L  = (u64*)shm;                  // epilogue lists (20.5 KB)

  const int t    = threadIdx.x;
  const int lane = t & 63;
  const int l31  = lane & 31;
  const int lh   = lane >> 5;
  const int w    = t >> 6;              // wave id
  const int wq   = t >> 7;              // wave row-half
  const int wc   = (t >> 6) & 1;        // wave col-half
  const int qbase = blockIdx.x * 128;

  if (t < 128) qs_lds[t] = qsq[qbase + t];

  // staging map: wave w, sub-instr i in {0,1}, lane covers logical row
  // sR0(+16 for i=1), k-chunk (lane&3)^((lane>>3)&3), 8 elems.
  const int sR0 = 2 * (w * 16 + (lane >> 3)) + ((lane >> 2) & 1);
  const int sC  = ((lane & 3) ^ ((lane >> 3) & 3)) << 3;
  const size_t qoff0 = (size_t)(qbase + sR0) * DD + sC;
  const size_t qoff1 = qoff0 + (size_t)16 * DD;
  const int d0 = (w * 2 + 0) * 512;     // LDS dst (u16) per wave/sub-instr
  const int d1 = (w * 2 + 1) * 512;

  // fragment-read bases (read side of the same fold+swizzle)
  const int fbA = (wq * 32 + (l31 >> 1)) * 64 + (l31 & 1) * 32;
  const int fbB = (wc * 32 + (l31 >> 1)) * 64 + (l31 & 1) * 32;
  const int fx  = (l31 >> 1) & 3;

  u64 lst[10];
#pragma unroll
  for (int i = 0; i < 10; ++i) lst[i] = 0ull;

  const int grow   = t >> 1;            // owned global row (0..127)
  const int gseg   = (t & 1) * 64;      // owned col segment
  const int dsrow  = grow & 63;
  const int mypass = grow >> 6;

  const int tile0 = (blockIdx.y * NT) / GY2;
  const int tile1 = ((blockIdx.y + 1) * NT) / GY2;

  for (int tile = tile0; tile < tile1; ++tile) {
    const int cbase = tile * 128;

    f32x16 acc[2][2];
#pragma unroll
    for (int rg = 0; rg < 2; ++rg)
#pragma unroll
      for (int cg = 0; cg < 2; ++cg)
#pragma unroll
        for (int e = 0; e < 16; ++e) acc[rg][cg][e] = 0.f;

    const size_t roff0 = (size_t)(cbase + sR0) * DD + sC;
    const size_t roff1 = roff0 + (size_t)16 * DD;

    for (int kt = 0; kt < 16; ++kt) {
      const int k0 = kt * 32;
      gl_lds16(Qhg + qoff0 + k0, Qh_l + d0);
      gl_lds16(Qhg + qoff1 + k0, Qh_l + d1);
      gl_lds16(Qlg + qoff0 + k0, Ql_l + d0);
      gl_lds16(Qlg + qoff1 + k0, Ql_l + d1);
      gl_lds16(Rhg + roff0 + k0, Rh_l + d0);
      gl_lds16(Rhg + roff1 + k0, Rh_l + d1);
      gl_lds16(Rlg + roff0 + k0, Rl_l + d0);
      gl_lds16(Rlg + roff1 + k0, Rl_l + d1);
      __syncthreads();                  // drains vmcnt -> LDS ready
#pragma unroll
      for (int ks = 0; ks < 2; ++ks) {
        const int xo = ((ks * 2 + lh) ^ fx) << 3;
        bf16x8 ah[2], al[2], bh[2], bl[2];
#pragma unroll
        for (int rg = 0; rg < 2; ++rg) {
          const int off = fbA + rg * 1024 + xo;
          ah[rg] = *reinterpret_cast<const bf16x8*>(Qh_l + off);
          al[rg] = *reinterpret_cast<const bf16x8*>(Ql_l + off);
        }
#pragma unroll
        for (int cg = 0; cg < 2; ++cg) {
          const int off = fbB + cg * 1024 + xo;
          bh[cg] = *reinterpret_cast<const bf16x8*>(Rh_l + off);
          bl[cg] = *reinterpret_cast<const bf16x8*>(Rl_l + off);
        }
        __builtin_amdgcn_s_setprio(1);
#pragma unroll
        for (int rg = 0; rg < 2; ++rg)
#pragma unroll
          for (int cg = 0; cg < 2; ++cg) {
            acc[rg][cg] = __builtin_amdgcn_mfma_f32_32x32x16_bf16(ah[rg], bh[cg], acc[rg][cg], 0, 0, 0);
            acc[rg][cg] = __builtin_amdgcn_mfma_f32_32x32x16_bf16(ah[rg], bl[cg], acc[rg][cg], 0, 0, 0);
            acc[rg][cg] = __builtin_amdgcn_mfma_f32_32x32x16_bf16(al[rg], bh[cg], acc[rg][cg], 0, 0, 0);
          }
        __builtin_amdgcn_s_setprio(0);
      }
      __syncthreads();                  // frag reads done before restage
    }

    // ---- dist + scan, two 64-row passes ----
    const float rs0 = rsq[cbase + wc * 64 + l31];
    const float rs1 = rsq[cbase + wc * 64 + 32 + l31];
    const bool v0 = (cbase + wc * 64 + l31) < ND;
    const bool v1 = (cbase + wc * 64 + 32 + l31) < ND;
#pragma unroll
    for (int h = 0; h < 2; ++h) {
      if (wq == h) {
        // C/D layout: col = lane&31, row = (e&3) + 8*(e>>2) + 4*lh (+32*rg)
#pragma unroll
        for (int rg = 0; rg < 2; ++rg)
#pragma unroll
          for (int e = 0; e < 16; ++e) {
            const int dr  = rg * 32 + (e & 3) + ((e >> 2) << 3) + (lh << 2);
            const float qsv = qs_lds[h * 64 + dr];
            float d0v = qsv + rs0 - 2.0f * acc[rg][0][e];
            u32 k0b = __float_as_uint(d0v);
            k0b ^= (k0b & 0x80000000u) ? 0xFFFFFFFFu : 0x80000000u;
            DS[dr * 128 + wc * 64 + l31] = v0 ? k0b : 0u;
            float d1v = qsv + rs1 - 2.0f * acc[rg][1][e];
            u32 k1b = __float_as_uint(d1v);
            k1b ^= (k1b & 0x80000000u) ? 0xFFFFFFFFu : 0x80000000u;
            DS[dr * 128 + wc * 64 + 32 + l31] = v1 ? k1b : 0u;
          }
      }
      __syncthreads();
      if (mypass == h) {
        const int colb = cbase + gseg;
#pragma unroll 4
        for (int cc = 0; cc < 64; ++cc) {
          const int c  = (cc + dsrow) & 63;    // rotation: banks 2-way (free)
          const u32 kb = DS[dsrow * 128 + gseg + c];
          const u64 key = ((u64)kb << 16) | (u64)(((colb + c) ^ 0xFFFF) & 0xFFFF);
          if (key > lst[9]) insert10(lst, key);
        }
      }
      __syncthreads();
    }
  }

  // ---- epilogue: merge the two col-segment lists per row; write 10/row ----
#pragma unroll
  for (int i = 0; i < 10; ++i) L[t * 10 + i] = lst[i];
  __syncthreads();
  if (t < 128) {
    u64 best[10];
#pragma unroll
    for (int i = 0; i < 10; ++i) best[i] = L[(2 * t) * 10 + i];
#pragma unroll
    for (int i = 0; i < 10; ++i) {
      u64 key = L[(2 * t + 1) * 10 + i];
      if (key <= best[9]) break;        // lists sorted desc
      insert10(best, key);
    }
    const size_t base = (size_t)blockIdx.y * 10;
#pragma unroll
    for (int j = 0; j < 10; ++j)
      cand[(base + j) * MQ + qbase + t] = best[j];
  }
}

// ---------------- kernel 3: merge candidates, labels, mode ----------------
__global__ __launch_bounds__(256) void knn_finalize(
    const u64* __restrict__ cand, float* __restrict__ out, int nSlots)
{
  __shared__ u64 ML[256][10];
  const int t   = threadIdx.x;
  const int row = blockIdx.x * 32 + (t >> 3);
  const int l8  = t & 7;
  u64 lst[10];
#pragma unroll
  for (int i = 0; i < 10; ++i) lst[i] = 0ull;
  for (int s2 = l8; s2 < nSlots; s2 += 8) {
    const u64 key = cand[(size_t)s2 * MQ + row];   // coalesced in row
    if (key > lst[9]) insert10(lst, key);
  }
#pragma unroll
  for (int i = 0; i < 10; ++i) ML[t][i] = lst[i];
  __syncthreads();
  if (l8 == 0) {
#pragma unroll
    for (int m = 1; m < 8; ++m) {
#pragma unroll
      for (int i = 0; i < 10; ++i) {
        const u64 key = ML[t + m][i];
        if (key <= lst[9]) break;
        insert10(lst, key);
      }
    }
    int best = 0, bestc = 0;
#pragma unroll
    for (int cls = 0; cls < 10; ++cls) {
      int cnt = 0;
#pragma unroll
      for (int j = 0; j < 10; ++j) {
        const int col = ((int)(lst[j] & 0xFFFFull)) ^ 0xFFFF;
        cnt += (col / 5000 == cls) ? 1 : 0;
      }
      if (cnt > bestc) { bestc = cnt; best = cls; }
    }
    out[row] = (float)best;
  }
}

extern "C" void kernel_launch(void* const* d_in, const int* in_sizes, int n_in,
                              void* d_out, int out_size, void* d_ws, size_t ws_size,
                              hipStream_t stream)
{
  const float* Q = (const float*)d_in[0];
  const float* R = (const float*)d_in[1];
  float* out = (float*)d_out;

  // ws: Qh 2M, Ql 2M, Rh 51.2M, Rl 51.2M, rsq/qsq 0.2M, cand 10.5M = 117 MB
  // (proven available: round-6 main path ran with 123 MB need)
  char* p = (char*)d_ws;
  u16* Qh = (u16*)p;                          p += (size_t)MQ * DD * 2;
  u16* Ql = (u16*)p;                          p += (size_t)MQ * DD * 2;
  u16* Rh = (u16*)p;                          p += (size_t)NDPAD * DD * 2;
  u16* Rl = (u16*)p;                          p += (size_t)NDPAD * DD * 2;
  float* rsq = (float*)p;                     p += (size_t)NDPAD * 4;
  float* qsq = (float*)p;                     p += (size_t)MQ * 4;
  u64* cand = (u64*)p;

  convert_kernel<<<(ND + MQ + 3) / 4, 256, 0, stream>>>(Q, R, Qh, Ql, Rh, Rl, rsq, qsq);
  knn_mfma_topk<<<dim3(MQ / 128, GY2), 256, 0, stream>>>(Qh, Ql, Rh, Rl, qsq, rsq, cand);
  knn_finalize<<<MQ / 32, 256, 0, stream>>>(cand, out, GY2 * 10);
}

// Round 8
// 1036.005 us; speedup vs baseline: 1.0224x; 1.0224x over previous
//
#include <hip/hip_runtime.h>

typedef unsigned long long u64;
typedef unsigned int u32;
typedef unsigned short u16;
using bf16x8 = __attribute__((ext_vector_type(8))) __bf16;
using f32x16 = __attribute__((ext_vector_type(16))) float;

#define MQ 2048
#define ND 50000
#define DD 512

constexpr int NT    = 391;              // col-tiles of 128 (391*128 = 50048)
constexpr int NDPAD = NT * 128;         // padded R rows for bf16 arrays
constexpr int GY2   = 64;               // y-chunks; grid = 16*64 = 1024 blocks
constexpr int SHB   = 65536;            // 2 x 32KB stage buffers; DS/L overlay buf0

__device__ __forceinline__ void insert10(u64 (&lst)[10], u64 key) {
  u64 cur = key;                        // lst sorted descending
#pragma unroll
  for (int p = 0; p < 10; ++p) {
    u64 a = lst[p];
    u64 mx = a > cur ? a : cur;
    cur    = a > cur ? cur : a;
    lst[p] = mx;
  }
}

__device__ __forceinline__ u32 bf_hi_rtn(float x) {   // bf16 RTNE, as bits
  u32 b = __float_as_uint(x);
  return (b + 0x7FFFu + ((b >> 16) & 1u)) >> 16;
}

__device__ __forceinline__ void gl_lds16(const u16* g, u16* l) {
  __builtin_amdgcn_global_load_lds(
      (const __attribute__((address_space(1))) u32*)g,
      (__attribute__((address_space(3))) u32*)l, 16, 0, 0);
}

// ---- kernel 1: fp32 -> bf16 hi/lo split + row sq-norms ----
__global__ __launch_bounds__(256) void convert_kernel(
    const float* __restrict__ Q, const float* __restrict__ R,
    u16* __restrict__ Qh, u16* __restrict__ Ql,
    u16* __restrict__ Rh, u16* __restrict__ Rl,
    float* __restrict__ rsq, float* __restrict__ qsq)
{
  const int wid  = blockIdx.x * 4 + (threadIdx.x >> 6);
  const int lane = threadIdx.x & 63;
  if (wid >= ND + MQ) return;
  const bool isR = wid < ND;
  const size_t row = isR ? (size_t)wid : (size_t)(wid - ND);
  const float* src = (isR ? R : Q) + row * DD;
  u16* hD = (isR ? Rh : Qh) + row * DD;
  u16* lD = (isR ? Rl : Ql) + row * DD;

  float s = 0.f;
#pragma unroll
  for (int it = 0; it < 2; ++it) {
    const int e = lane * 4 + it * 256;
    const float4 v = *reinterpret_cast<const float4*>(src + e);
    s += v.x * v.x + v.y * v.y + v.z * v.z + v.w * v.w;
    const u32 h0 = bf_hi_rtn(v.x), h1 = bf_hi_rtn(v.y), h2 = bf_hi_rtn(v.z), h3 = bf_hi_rtn(v.w);
    const u32 g0 = bf_hi_rtn(v.x - __uint_as_float(h0 << 16));
    const u32 g1 = bf_hi_rtn(v.y - __uint_as_float(h1 << 16));
    const u32 g2 = bf_hi_rtn(v.z - __uint_as_float(h2 << 16));
    const u32 g3 = bf_hi_rtn(v.w - __uint_as_float(h3 << 16));
    *reinterpret_cast<u64*>(hD + e) = (u64)h0 | ((u64)h1 << 16) | ((u64)h2 << 32) | ((u64)h3 << 48);
    *reinterpret_cast<u64*>(lD + e) = (u64)g0 | ((u64)g1 << 16) | ((u64)g2 << 32) | ((u64)g3 << 48);
  }
#pragma unroll
  for (int off = 32; off > 0; off >>= 1) s += __shfl_down(s, off, 64);
  if (lane == 0) {
    if (isR) rsq[row] = s;
    else     qsq[row] = s;
  }
}

// ---- kernel 2: MFMA GEMM-distance + fused top-10 ----
// 128x128 tile, BK=32, 2-phase double-buffered global_load_lds pipeline.
// LDS per buffer: Qh|Ql|Rh|Rl, each [64 ldsrows][8 slots][8 bf16]; logical row
// r = 2*ldsrow + half. Slot for (half,chunk) stored at (half*4+chunk)^(ldsrow&7)
// -> b128 frag reads 2-way banked (free). Stage = linear LDS dst + inverse-
// swizzled GLOBAL src (rule 21). No launch_bounds min-waves: avoid r7's spill.
__global__ __launch_bounds__(256) void knn_mfma_topk(
    const u16* __restrict__ Qhg, const u16* __restrict__ Qlg,
    const u16* __restrict__ Rhg, const u16* __restrict__ Rlg,
    const float* __restrict__ qsq, const float* __restrict__ rsq,
    u64* __restrict__ cand)
{
  __shared__ __align__(16) char shm[SHB];
  __shared__ float qs_lds[128];
  u16* B0 = (u16*)shm;                  // buffer b at u16 offset b*16384
  u32* DS = (u32*)shm;                  // [64][128] dist keys (overlays buf0)
  u64* L  = (u64*)shm;                  // epilogue lists (overlays buf0)

  const int t    = threadIdx.x;
  const int lane = t & 63;
  const int l31  = lane & 31;
  const int lh   = lane >> 5;
  const int w    = t >> 6;              // wave id
  const int wq   = t >> 7;              // wave row-half of C
  const int wc   = (t >> 6) & 1;        // wave col-half of C

  // XCD-bijective decode: all 16 q-blocks of a y-chunk on one XCD (bid%8)
  const int b    = blockIdx.x;
  const int ych  = (b & 7) + 8 * (b >> 7);
  const int qblk = (b >> 3) & 15;
  const int qbase = qblk * 128;

  if (t < 128) qs_lds[t] = qsq[qbase + t];

  // staging source map (inverse of the slot swizzle; dest is linear in lane)
  const int sgrp  = lane >> 3;                    // ldsrow & 7 for this lane
  const int sslot = (lane & 7) ^ sgrp;            // global slot = half*4+chunk
  const int sR2   = 2 * (w * 16 + sgrp) + (sslot >> 2);   // logical row, instr 0
  const int sC    = (sslot & 3) << 3;             // k-element offset
  const size_t qoff0 = (size_t)(qbase + sR2) * DD + sC;
  const size_t qoff1 = qoff0 + (size_t)16 * DD;
  const int dW = w * 1024;                        // per-wave dst base (u16)

  auto stage = [&](int buf, int tile_, int kt_) {
    const size_t k0 = (size_t)kt_ * 32;
    const size_t ro0 = (size_t)(tile_ * 128 + sR2) * DD + sC + k0;
    u16* Bb = B0 + buf * 16384;
    gl_lds16(Qhg + qoff0 + k0, Bb + dW);
    gl_lds16(Qhg + qoff1 + k0, Bb + dW + 512);
    gl_lds16(Qlg + qoff0 + k0, Bb + 4096 + dW);
    gl_lds16(Qlg + qoff1 + k0, Bb + 4096 + dW + 512);
    gl_lds16(Rhg + ro0,                 Bb + 8192 + dW);
    gl_lds16(Rhg + ro0 + (size_t)16*DD, Bb + 8192 + dW + 512);
    gl_lds16(Rlg + ro0,                 Bb + 12288 + dW);
    gl_lds16(Rlg + ro0 + (size_t)16*DD, Bb + 12288 + dW + 512);
  };

  // fragment-read constants
  const int rA  = l31 >> 1;                       // row-pair index 0..15
  const int xA  = rA & 7;                         // slot XOR
  const int hA  = (l31 & 1) << 2;                 // half bit in slot

  u64 lst[10];
#pragma unroll
  for (int i = 0; i < 10; ++i) lst[i] = 0ull;

  const int grow   = t >> 1;            // scan: owned global row (0..127)
  const int gseg   = (t & 1) * 64;      // scan: owned col segment
  const int dsrow  = grow & 63;
  const int mypass = grow >> 6;

  const int tile0 = (ych * NT) / GY2;
  const int tile1 = ((ych + 1) * NT) / GY2;

  bool primed = false;
  for (int tile = tile0; tile < tile1; ++tile) {
    const int cbase = tile * 128;

    f32x16 acc[2][2];
#pragma unroll
    for (int rg = 0; rg < 2; ++rg)
#pragma unroll
      for (int cg = 0; cg < 2; ++cg)
#pragma unroll
        for (int e = 0; e < 16; ++e) acc[rg][cg][e] = 0.f;

    if (!primed) { stage(1, tile, 0); __syncthreads(); primed = true; }

    for (int kt = 0; kt < 16; ++kt) {
      const int cur = (kt + 1) & 1;     // kt0 reads buf1 ... kt15 reads buf0
      if (kt < 15)                stage(cur ^ 1, tile, kt + 1);
      else if (tile + 1 < tile1)  stage(1, tile + 1, 0);   // next-tile prefetch
      u16* Bb = B0 + cur * 16384;
#pragma unroll
      for (int ks = 0; ks < 2; ++ks) {
        const int c = (ks << 1) + lh;   // k-chunk 0..3 of this BK=32 slice
        bf16x8 ah[2], al[2], bh[2], bl[2];
#pragma unroll
        for (int rg = 0; rg < 2; ++rg) {
          const int off = (wq * 32 + rg * 16 + rA) * 64 + (((hA + c) ^ xA) << 3);
          ah[rg] = *reinterpret_cast<const bf16x8*>(Bb + off);
          al[rg] = *reinterpret_cast<const bf16x8*>(Bb + 4096 + off);
        }
#pragma unroll
        for (int cg = 0; cg < 2; ++cg) {
          const int off = (wc * 32 + cg * 16 + rA) * 64 + (((hA + c) ^ xA) << 3);
          bh[cg] = *reinterpret_cast<const bf16x8*>(Bb + 8192 + off);
          bl[cg] = *reinterpret_cast<const bf16x8*>(Bb + 12288 + off);
        }
        __builtin_amdgcn_s_setprio(1);
#pragma unroll
        for (int rg = 0; rg < 2; ++rg)
#pragma unroll
          for (int cg = 0; cg < 2; ++cg) {
            acc[rg][cg] = __builtin_amdgcn_mfma_f32_32x32x16_bf16(ah[rg], bh[cg], acc[rg][cg], 0, 0, 0);
            acc[rg][cg] = __builtin_amdgcn_mfma_f32_32x32x16_bf16(ah[rg], bl[cg], acc[rg][cg], 0, 0, 0);
            acc[rg][cg] = __builtin_amdgcn_mfma_f32_32x32x16_bf16(al[rg], bh[cg], acc[rg][cg], 0, 0, 0);
          }
        __builtin_amdgcn_s_setprio(0);
      }
      __syncthreads();                  // auto vmcnt(0): drains this step's stage
    }

    // ---- dist + scan, two 64-row passes (DS overlays buf0; buf1 = prefetch) ----
    const float rs0 = rsq[cbase + wc * 64 + l31];
    const float rs1 = rsq[cbase + wc * 64 + 32 + l31];
    const bool v0 = (cbase + wc * 64 + l31) < ND;
    const bool v1 = (cbase + wc * 64 + 32 + l31) < ND;
#pragma unroll
    for (int h = 0; h < 2; ++h) {
      if (wq == h) {
        // C/D layout: col = lane&31, row = (e&3) + 8*(e>>2) + 4*lh (+32*rg)
#pragma unroll
        for (int rg = 0; rg < 2; ++rg)
#pragma unroll
          for (int e = 0; e < 16; ++e) {
            const int dr  = rg * 32 + (e & 3) + ((e >> 2) << 3) + (lh << 2);
            const float qsv = qs_lds[h * 64 + dr];
            float d0v = qsv + rs0 - 2.0f * acc[rg][0][e];
            u32 k0b = __float_as_uint(d0v);
            k0b ^= (k0b & 0x80000000u) ? 0xFFFFFFFFu : 0x80000000u;
            DS[dr * 128 + wc * 64 + l31] = v0 ? k0b : 0u;
            float d1v = qsv + rs1 - 2.0f * acc[rg][1][e];
            u32 k1b = __float_as_uint(d1v);
            k1b ^= (k1b & 0x80000000u) ? 0xFFFFFFFFu : 0x80000000u;
            DS[dr * 128 + wc * 64 + 32 + l31] = v1 ? k1b : 0u;
          }
      }
      __syncthreads();
      if (mypass == h) {
        const int colb = cbase + gseg;
#pragma unroll 4
        for (int cc = 0; cc < 64; ++cc) {
          const int c  = (cc + dsrow) & 63;    // rotation -> 2-way banks (free)
          const u32 kb = DS[dsrow * 128 + gseg + c];
          const u64 key = ((u64)kb << 16) | (u64)(((colb + c) ^ 0xFFFF) & 0xFFFF);
          if (key > lst[9]) insert10(lst, key);
        }
      }
      __syncthreads();
    }
  }

  // ---- epilogue: merge the two col-segment lists per row; write 10/row ----
#pragma unroll
  for (int i = 0; i < 10; ++i) L[t * 10 + i] = lst[i];
  __syncthreads();
  if (t < 128) {
    u64 best[10];
#pragma unroll
    for (int i = 0; i < 10; ++i) best[i] = L[(2 * t) * 10 + i];
#pragma unroll
    for (int i = 0; i < 10; ++i) {
      u64 key = L[(2 * t + 1) * 10 + i];
      if (key <= best[9]) break;        // lists sorted desc
      insert10(best, key);
    }
    const size_t base = (size_t)ych * 10;
#pragma unroll
    for (int j = 0; j < 10; ++j)
      cand[(base + j) * MQ + qbase + t] = best[j];
  }
}

// ---------------- kernel 3: merge candidates, labels, mode ----------------
__global__ __launch_bounds__(256) void knn_finalize(
    const u64* __restrict__ cand, float* __restrict__ out, int nSlots)
{
  __shared__ u64 ML[256][10];
  const int t   = threadIdx.x;
  const int row = blockIdx.x * 32 + (t >> 3);
  const int l8  = t & 7;
  u64 lst[10];
#pragma unroll
  for (int i = 0; i < 10; ++i) lst[i] = 0ull;
  for (int s2 = l8; s2 < nSlots; s2 += 8) {
    const u64 key = cand[(size_t)s2 * MQ + row];   // coalesced in row
    if (key > lst[9]) insert10(lst, key);
  }
#pragma unroll
  for (int i = 0; i < 10; ++i) ML[t][i] = lst[i];
  __syncthreads();
  if (l8 == 0) {
#pragma unroll
    for (int m = 1; m < 8; ++m) {
#pragma unroll
      for (int i = 0; i < 10; ++i) {
        const u64 key = ML[t + m][i];
        if (key <= lst[9]) break;
        insert10(lst, key);
      }
    }
    int best = 0, bestc = 0;
#pragma unroll
    for (int cls = 0; cls < 10; ++cls) {
      int cnt = 0;
#pragma unroll
      for (int j = 0; j < 10; ++j) {
        const int col = ((int)(lst[j] & 0xFFFFull)) ^ 0xFFFF;
        cnt += (col / 5000 == cls) ? 1 : 0;
      }
      if (cnt > bestc) { bestc = cnt; best = cls; }
    }
    out[row] = (float)best;
  }
}

extern "C" void kernel_launch(void* const* d_in, const int* in_sizes, int n_in,
                              void* d_out, int out_size, void* d_ws, size_t ws_size,
                              hipStream_t stream)
{
  const float* Q = (const float*)d_in[0];
  const float* R = (const float*)d_in[1];
  float* out = (float*)d_out;

  // ws: Qh 2M, Ql 2M, Rh 51.2M, Rl 51.2M, rsq/qsq 0.2M, cand 10.5M = 117 MB
  // (proven: round-6 main path ran with a 123 MB layout)
  char* p = (char*)d_ws;
  u16* Qh = (u16*)p;                          p += (size_t)MQ * DD * 2;
  u16* Ql = (u16*)p;                          p += (size_t)MQ * DD * 2;
  u16* Rh = (u16*)p;                          p += (size_t)NDPAD * DD * 2;
  u16* Rl = (u16*)p;                          p += (size_t)NDPAD * DD * 2;
  float* rsq = (float*)p;                     p += (size_t)NDPAD * 4;
  float* qsq = (float*)p;                     p += (size_t)MQ * 4;
  u64* cand = (u64*)p;

  convert_kernel<<<(ND + MQ + 3) / 4, 256, 0, stream>>>(Q, R, Qh, Ql, Rh, Rl, rsq, qsq);
  knn_mfma_topk<<<16 * GY2, 256, 0, stream>>>(Qh, Ql, Rh, Rl, qsq, rsq, cand);
  knn_finalize<<<MQ / 32, 256, 0, stream>>>(cand, out, GY2 * 10);
}